// Round 5
// baseline (964.619 us; speedup 1.0000x reference)
//
#include <hip/hip_runtime.h>

// APPNP: K steps of D^{-1/2} A D^{-1/2} propagation + teleport, then MLP.
// CSR built once per call; per-edge weight folds (1-alpha)*norm[src]*norm[dst].
// R5: fix mlp phase-2 LDS mapping (nA=ng2, nB=ng2+16 -> lane stride 260 dwords
// == 4 mod 32 -> 2-way bank aliasing, which is free; R4's nA=2*ng2 was 4-way,
// 6.4e6 conflict cycles).

#define N_NODES 100000
#define N_EDGES 800000
#define D_DATA  100
#define H_DIM   256
#define N_CLS   47
#define K_STEPS 10
#define ALPHA   0.1f

#define SCAN_NB    200   // blocks in the parallel scan
#define SCAN_CHUNK 500   // elements per block; 200*500 == N_NODES

// ---------------- CSR build ----------------

__global__ void deg_kernel(const int* __restrict__ dst, int* __restrict__ deg, int e) {
    int i = blockIdx.x * blockDim.x + threadIdx.x;
    if (i < e) atomicAdd(&deg[dst[i]], 1);
}

// pass 1: per-block sums of deg
__global__ __launch_bounds__(256) void scan_partial_kernel(
        const int* __restrict__ deg, int* __restrict__ partials) {
    __shared__ int red[256];
    int t = threadIdx.x;
    int base = blockIdx.x * SCAN_CHUNK;
    int s = 0;
    int i0 = 2 * t, i1 = 2 * t + 1;
    if (i0 < SCAN_CHUNK) s += deg[base + i0];
    if (i1 < SCAN_CHUNK) s += deg[base + i1];
    red[t] = s;
    __syncthreads();
    for (int off = 128; off > 0; off >>= 1) {
        if (t < off) red[t] += red[t + off];
        __syncthreads();
    }
    if (t == 0) partials[blockIdx.x] = red[0];
}

// pass 2: single block scans the 200 partials (exclusive)
__global__ __launch_bounds__(256) void scan_top_kernel(
        const int* __restrict__ partials, int* __restrict__ pofs,
        int* __restrict__ row_ptr) {
    __shared__ int s[256];
    int t = threadIdx.x;
    s[t] = (t < SCAN_NB) ? partials[t] : 0;
    __syncthreads();
    for (int off = 1; off < 256; off <<= 1) {
        int v = (t >= off) ? s[t - off] : 0;
        __syncthreads();
        s[t] += v;
        __syncthreads();
    }
    if (t < SCAN_NB) pofs[t] = s[t] - partials[t];   // exclusive
    if (t == 0) row_ptr[N_NODES] = N_EDGES;          // total degree is fixed
}

// pass 3: block-local exclusive scan + emit row_ptr and norm
__global__ __launch_bounds__(256) void scan_emit_kernel(
        const int* __restrict__ deg, const int* __restrict__ pofs,
        int* __restrict__ row_ptr, float* __restrict__ norm) {
    __shared__ int s[256];
    int t = threadIdx.x;
    int base = blockIdx.x * SCAN_CHUNK;
    int i0 = 2 * t, i1 = 2 * t + 1;
    int d0 = (i0 < SCAN_CHUNK) ? deg[base + i0] : 0;
    int d1 = (i1 < SCAN_CHUNK) ? deg[base + i1] : 0;
    s[t] = d0 + d1;
    __syncthreads();
    for (int off = 1; off < 256; off <<= 1) {
        int v = (t >= off) ? s[t - off] : 0;
        __syncthreads();
        s[t] += v;
        __syncthreads();
    }
    int p = s[t] - (d0 + d1) + pofs[blockIdx.x];   // exclusive + block offset
    if (i0 < SCAN_CHUNK) {
        row_ptr[base + i0] = p;
        norm[base + i0] = rsqrtf((float)max(d0, 1));
    }
    if (i1 < SCAN_CHUNK) {
        row_ptr[base + i1] = p + d0;
        norm[base + i1] = rsqrtf((float)max(d1, 1));
    }
}

__global__ void scatter_kernel(const int* __restrict__ src, const int* __restrict__ dst,
                               const float* __restrict__ norm,
                               const int* __restrict__ row_ptr, int* __restrict__ fill,
                               float2* __restrict__ ew, int e) {
    int i = blockIdx.x * blockDim.x + threadIdx.x;
    if (i < e) {
        int d = dst[i], s = src[i];
        int pos = row_ptr[d] + atomicAdd(&fill[d], 1);
        float w = (1.0f - ALPHA) * norm[s] * norm[d];
        ew[pos] = make_float2(w, __int_as_float(s));
    }
}

// W2 [256][47] -> W2t [48][256], zero-padded col 47.
__global__ void transpose_w2_kernel(const float* __restrict__ W2, float* __restrict__ W2t) {
    int idx = blockIdx.x * blockDim.x + threadIdx.x;
    if (idx < 48 * H_DIM) {
        int c = idx >> 8;
        int j = idx & (H_DIM - 1);
        W2t[c * H_DIM + j] = (c < N_CLS) ? W2[j * N_CLS + c] : 0.f;
    }
}

// ---------------- propagation ----------------
// One wave per node; lanes 0..49 each hold a float2 of the 100-float row
// (one 8B gather instruction covers the whole 400B row). x8 unroll keeps
// 8 row-gathers in flight.

__global__ __launch_bounds__(256) void prop_kernel(
        const float* __restrict__ hin, const float* __restrict__ x,
        const int* __restrict__ row_ptr, const float2* __restrict__ ew,
        float* __restrict__ hout, int n_nodes) {
    int lane = threadIdx.x & 63;
    int node = __builtin_amdgcn_readfirstlane(blockIdx.x * 4 + (threadIdx.x >> 6));
    if (node >= n_nodes) return;
    int beg = __builtin_amdgcn_readfirstlane(row_ptr[node]);
    int end = __builtin_amdgcn_readfirstlane(row_ptr[node + 1]);
    bool act = lane < (D_DATA / 2);   // 50 lanes carry the row
    float ax = 0.f, ay = 0.f, bx = 0.f, by = 0.f;
    float cx = 0.f, cy = 0.f, dx = 0.f, dy = 0.f;
    int e = beg;
    for (; e + 8 <= end; e += 8) {
        float2 p[8];
#pragma unroll
        for (int j = 0; j < 8; ++j) p[j] = ew[e + j];          // uniform -> s_load
        float2 v[8];
#pragma unroll
        for (int j = 0; j < 8; ++j) {
            const float2* r = (const float2*)(hin + (size_t)__float_as_int(p[j].y) * D_DATA);
            v[j] = act ? r[lane] : make_float2(0.f, 0.f);
        }
        ax += p[0].x * v[0].x; ay += p[0].x * v[0].y;
        bx += p[1].x * v[1].x; by += p[1].x * v[1].y;
        cx += p[2].x * v[2].x; cy += p[2].x * v[2].y;
        dx += p[3].x * v[3].x; dy += p[3].x * v[3].y;
        ax += p[4].x * v[4].x; ay += p[4].x * v[4].y;
        bx += p[5].x * v[5].x; by += p[5].x * v[5].y;
        cx += p[6].x * v[6].x; cy += p[6].x * v[6].y;
        dx += p[7].x * v[7].x; dy += p[7].x * v[7].y;
    }
    for (; e < end; ++e) {
        float2 p = ew[e];
        const float2* r = (const float2*)(hin + (size_t)__float_as_int(p.y) * D_DATA);
        float2 v = act ? r[lane] : make_float2(0.f, 0.f);
        ax += p.x * v.x; ay += p.x * v.y;
    }
    if (act) {
        float sx = (ax + bx) + (cx + dx);
        float sy = (ay + by) + (cy + dy);
        const float2* x2 = (const float2*)(x + (size_t)node * D_DATA);
        float2 xv = x2[lane];
        float2 o;
        o.x = sx + ALPHA * xv.x;
        o.y = sy + ALPHA * xv.y;
        ((float2*)(hout + (size_t)node * D_DATA))[lane] = o;
    }
}

// ---------------- fused MLP ----------------
// Block = 256 threads, 32 nodes. Phase 1: thread (cg=t&63 -> 4 cols,
// ng=t>>6 -> 8 nodes); h rows wave-uniform -> scalar loads; W1 pipelined.
// Phase 2: thread (cg2=t>>4 -> 3 cols, ng2=t&15 -> nodes ng2 and ng2+16):
// zs lane stride = 260 dwords == 4 mod 32 -> 2-way bank aliasing (free);
// the 4 cg2 groups read identical addresses (broadcast).

#define TN 32
#define HP 260

__global__ __launch_bounds__(256, 4) void mlp_kernel(
        const float* __restrict__ h,
        const float* __restrict__ W1, const float* __restrict__ b1,
        const float* __restrict__ W2t, const float* __restrict__ b2,
        float* __restrict__ out, int n_nodes) {
    __shared__ float zs[TN][HP];   // 32.5 KB -> 4 blocks/CU
    int tid = threadIdx.x;
    int node0 = blockIdx.x * TN;

    // ---- phase 1: z = relu(h @ W1 + b1) ----
    {
        int cg = tid & 63;
        int ng = tid >> 6;
        const float4* hrow[8];
#pragma unroll
        for (int i = 0; i < 8; ++i) {
            int r = __builtin_amdgcn_readfirstlane(node0 + ng * 8 + i);
            hrow[i] = (const float4*)(h + (size_t)r * D_DATA);
        }
        float acc[8][4];
        float4 bv = *(const float4*)(b1 + 4 * cg);
#pragma unroll
        for (int i = 0; i < 8; ++i) {
            acc[i][0] = bv.x; acc[i][1] = bv.y; acc[i][2] = bv.z; acc[i][3] = bv.w;
        }
        float4 wv[4], wn[4];
#pragma unroll
        for (int k = 0; k < 4; ++k)
            wv[k] = *(const float4*)&W1[(size_t)k * H_DIM + 4 * cg];
        for (int d4 = 0; d4 < D_DATA / 4; ++d4) {
            if (d4 + 1 < D_DATA / 4) {
#pragma unroll
                for (int k = 0; k < 4; ++k)
                    wn[k] = *(const float4*)&W1[(size_t)((d4 + 1) * 4 + k) * H_DIM + 4 * cg];
            }
            float4 hv[8];
#pragma unroll
            for (int i = 0; i < 8; ++i) hv[i] = hrow[i][d4];   // scalar pipe
#pragma unroll
            for (int i = 0; i < 8; ++i) {
                acc[i][0] += hv[i].x * wv[0].x + hv[i].y * wv[1].x + hv[i].z * wv[2].x + hv[i].w * wv[3].x;
                acc[i][1] += hv[i].x * wv[0].y + hv[i].y * wv[1].y + hv[i].z * wv[2].y + hv[i].w * wv[3].y;
                acc[i][2] += hv[i].x * wv[0].z + hv[i].y * wv[1].z + hv[i].z * wv[2].z + hv[i].w * wv[3].z;
                acc[i][3] += hv[i].x * wv[0].w + hv[i].y * wv[1].w + hv[i].z * wv[2].w + hv[i].w * wv[3].w;
            }
#pragma unroll
            for (int k = 0; k < 4; ++k) wv[k] = wn[k];
        }
#pragma unroll
        for (int i = 0; i < 8; ++i) {
            float4 t;
            t.x = fmaxf(acc[i][0], 0.f); t.y = fmaxf(acc[i][1], 0.f);
            t.z = fmaxf(acc[i][2], 0.f); t.w = fmaxf(acc[i][3], 0.f);
            *(float4*)&zs[ng * 8 + i][4 * cg] = t;
        }
    }
    __syncthreads();

    // ---- phase 2: out = z @ W2 + b2 ----
    {
        int cg2 = tid >> 4;    // 16 col groups of 3; 4 distinct per wave
        int ng2 = tid & 15;    // node index
        int col0 = cg2 * 3;
        int nA = ng2, nB = ng2 + 16;   // lane stride 260 dwords: 2-way (free)
        float acc2[2][3];
#pragma unroll
        for (int cc = 0; cc < 3; ++cc) {
            int c = col0 + cc;
            float bb = (c < N_CLS) ? b2[c] : 0.f;
            acc2[0][cc] = bb; acc2[1][cc] = bb;
        }
        for (int j4 = 0; j4 < H_DIM / 4; ++j4) {
            float4 z0 = *(const float4*)&zs[nA][j4 * 4];
            float4 z1 = *(const float4*)&zs[nB][j4 * 4];
#pragma unroll
            for (int cc = 0; cc < 3; ++cc) {
                float4 w = *(const float4*)&W2t[(size_t)(col0 + cc) * H_DIM + j4 * 4];
                acc2[0][cc] += z0.x * w.x + z0.y * w.y + z0.z * w.z + z0.w * w.w;
                acc2[1][cc] += z1.x * w.x + z1.y * w.y + z1.z * w.z + z1.w * w.w;
            }
        }
#pragma unroll
        for (int n = 0; n < 2; ++n)
#pragma unroll
            for (int cc = 0; cc < 3; ++cc) {
                int c = col0 + cc;
                int gn = node0 + (n == 0 ? nA : nB);
                if (c < N_CLS && gn < n_nodes)
                    out[(size_t)gn * N_CLS + c] = acc2[n][cc];
            }
    }
}

// ---------------- launch ----------------

static inline size_t align_up(size_t v, size_t a) { return (v + a - 1) & ~(a - 1); }

extern "C" void kernel_launch(void* const* d_in, const int* in_sizes, int n_in,
                              void* d_out, int out_size, void* d_ws, size_t ws_size,
                              hipStream_t stream) {
    const float* x   = (const float*)d_in[0];
    const int*   src = (const int*)d_in[1];
    const int*   dst = (const int*)d_in[2];
    const float* W1  = (const float*)d_in[3];
    const float* b1  = (const float*)d_in[4];
    const float* W2  = (const float*)d_in[5];
    const float* b2  = (const float*)d_in[6];
    float* out = (float*)d_out;

    char* p = (char*)d_ws;
    size_t off = 0;
    int* deg = (int*)(p + off);           off = align_up(off + N_NODES * 4, 256);
    int* row_ptr = (int*)(p + off);       off = align_up(off + (N_NODES + 1) * 4, 256);
    int* fill = (int*)(p + off);          off = align_up(off + N_NODES * 4, 256);
    float* norm = (float*)(p + off);      off = align_up(off + N_NODES * 4, 256);
    int* partials = (int*)(p + off);      off = align_up(off + SCAN_NB * 4, 256);
    int* pofs = (int*)(p + off);          off = align_up(off + SCAN_NB * 4, 256);
    float2* ew = (float2*)(p + off);      off = align_up(off + N_EDGES * 8, 256);
    float* hA = (float*)(p + off);        off = align_up(off + (size_t)N_NODES * D_DATA * 4, 256);
    float* hB = (float*)(p + off);        off = align_up(off + (size_t)N_NODES * D_DATA * 4, 256);
    (void)ws_size;
    float* W2t = (float*)fill;   // fill is dead after scatter_kernel

    hipMemsetAsync(deg, 0, N_NODES * 4, stream);
    hipMemsetAsync(fill, 0, N_NODES * 4, stream);

    int eb = (N_EDGES + 255) / 256;
    deg_kernel<<<eb, 256, 0, stream>>>(dst, deg, N_EDGES);
    scan_partial_kernel<<<SCAN_NB, 256, 0, stream>>>(deg, partials);
    scan_top_kernel<<<1, 256, 0, stream>>>(partials, pofs, row_ptr);
    scan_emit_kernel<<<SCAN_NB, 256, 0, stream>>>(deg, pofs, row_ptr, norm);
    scatter_kernel<<<eb, 256, 0, stream>>>(src, dst, norm, row_ptr, fill, ew, N_EDGES);
    transpose_w2_kernel<<<(48 * H_DIM + 255) / 256, 256, 0, stream>>>(W2, W2t);

    int pb = N_NODES / 4;   // 4 waves (nodes) per block
    const float* hin = x;
    float* houts[2] = {hA, hB};
    for (int k = 0; k < K_STEPS; ++k) {
        float* ho = houts[k & 1];
        prop_kernel<<<pb, 256, 0, stream>>>(hin, x, row_ptr, ew, ho, N_NODES);
        hin = ho;
    }

    int mb = N_NODES / TN;
    mlp_kernel<<<mb, 256, 0, stream>>>(hin, W1, b1, W2t, b2, out, N_NODES);
}

// Round 6
// 806.619 us; speedup vs baseline: 1.1959x; 1.1959x over previous
//
#include <hip/hip_runtime.h>
#include <hip/hip_fp16.h>

// APPNP: K steps of D^{-1/2} A D^{-1/2} propagation + teleport, then MLP.
// R6: intermediate h stored as fp16 (fp32 accumulate, round on store only).
// A gathered row drops 400B/7-8 lines -> 200B/exactly 4 lines (1.75x less
// LLC line traffic); h-writes halve. Final step writes fp32 for the MLP.

#define N_NODES 100000
#define N_EDGES 800000
#define D_DATA  100
#define H_DIM   256
#define N_CLS   47
#define K_STEPS 10
#define ALPHA   0.1f

#define SCAN_NB    200
#define SCAN_CHUNK 500   // 200*500 == N_NODES

// ---------------- CSR build ----------------

__global__ void deg_kernel(const int* __restrict__ dst, int* __restrict__ deg, int e) {
    int i = blockIdx.x * blockDim.x + threadIdx.x;
    if (i < e) atomicAdd(&deg[dst[i]], 1);
}

__global__ __launch_bounds__(256) void scan_partial_kernel(
        const int* __restrict__ deg, int* __restrict__ partials) {
    __shared__ int red[256];
    int t = threadIdx.x;
    int base = blockIdx.x * SCAN_CHUNK;
    int s = 0;
    int i0 = 2 * t, i1 = 2 * t + 1;
    if (i0 < SCAN_CHUNK) s += deg[base + i0];
    if (i1 < SCAN_CHUNK) s += deg[base + i1];
    red[t] = s;
    __syncthreads();
    for (int off = 128; off > 0; off >>= 1) {
        if (t < off) red[t] += red[t + off];
        __syncthreads();
    }
    if (t == 0) partials[blockIdx.x] = red[0];
}

__global__ __launch_bounds__(256) void scan_top_kernel(
        const int* __restrict__ partials, int* __restrict__ pofs,
        int* __restrict__ row_ptr) {
    __shared__ int s[256];
    int t = threadIdx.x;
    s[t] = (t < SCAN_NB) ? partials[t] : 0;
    __syncthreads();
    for (int off = 1; off < 256; off <<= 1) {
        int v = (t >= off) ? s[t - off] : 0;
        __syncthreads();
        s[t] += v;
        __syncthreads();
    }
    if (t < SCAN_NB) pofs[t] = s[t] - partials[t];
    if (t == 0) row_ptr[N_NODES] = N_EDGES;
}

__global__ __launch_bounds__(256) void scan_emit_kernel(
        const int* __restrict__ deg, const int* __restrict__ pofs,
        int* __restrict__ row_ptr, float* __restrict__ norm) {
    __shared__ int s[256];
    int t = threadIdx.x;
    int base = blockIdx.x * SCAN_CHUNK;
    int i0 = 2 * t, i1 = 2 * t + 1;
    int d0 = (i0 < SCAN_CHUNK) ? deg[base + i0] : 0;
    int d1 = (i1 < SCAN_CHUNK) ? deg[base + i1] : 0;
    s[t] = d0 + d1;
    __syncthreads();
    for (int off = 1; off < 256; off <<= 1) {
        int v = (t >= off) ? s[t - off] : 0;
        __syncthreads();
        s[t] += v;
        __syncthreads();
    }
    int p = s[t] - (d0 + d1) + pofs[blockIdx.x];
    if (i0 < SCAN_CHUNK) {
        row_ptr[base + i0] = p;
        norm[base + i0] = rsqrtf((float)max(d0, 1));
    }
    if (i1 < SCAN_CHUNK) {
        row_ptr[base + i1] = p + d0;
        norm[base + i1] = rsqrtf((float)max(d1, 1));
    }
}

__global__ void scatter_kernel(const int* __restrict__ src, const int* __restrict__ dst,
                               const float* __restrict__ norm,
                               const int* __restrict__ row_ptr, int* __restrict__ fill,
                               float2* __restrict__ ew, int e) {
    int i = blockIdx.x * blockDim.x + threadIdx.x;
    if (i < e) {
        int d = dst[i], s = src[i];
        int pos = row_ptr[d] + atomicAdd(&fill[d], 1);
        float w = (1.0f - ALPHA) * norm[s] * norm[d];
        ew[pos] = make_float2(w, __int_as_float(s));
    }
}

__global__ void transpose_w2_kernel(const float* __restrict__ W2, float* __restrict__ W2t) {
    int idx = blockIdx.x * blockDim.x + threadIdx.x;
    if (idx < 48 * H_DIM) {
        int c = idx >> 8;
        int j = idx & (H_DIM - 1);
        W2t[c * H_DIM + j] = (c < N_CLS) ? W2[j * N_CLS + c] : 0.f;
    }
}

// x (fp32) -> x16 (fp16), one half2 per thread
__global__ void convert_x16_kernel(const float2* __restrict__ x2,
                                   __half2* __restrict__ x16, int n) {
    int i = blockIdx.x * blockDim.x + threadIdx.x;
    if (i < n) x16[i] = __float22half2_rn(x2[i]);
}

// ---------------- propagation ----------------
// One wave per node; lanes 0..49 each read a half2 (4B) of the 200B fp16 row.
// fp32 accumulate; teleport from fp32 x; store fp16 (prop16) or fp32 (final).

__global__ __launch_bounds__(256) void prop16_kernel(
        const __half* __restrict__ hin, const float* __restrict__ x,
        const int* __restrict__ row_ptr, const float2* __restrict__ ew,
        __half* __restrict__ hout, int n_nodes) {
    int lane = threadIdx.x & 63;
    int node = __builtin_amdgcn_readfirstlane(blockIdx.x * 4 + (threadIdx.x >> 6));
    if (node >= n_nodes) return;
    int beg = __builtin_amdgcn_readfirstlane(row_ptr[node]);
    int end = __builtin_amdgcn_readfirstlane(row_ptr[node + 1]);
    bool act = lane < (D_DATA / 2);
    float ax = 0.f, ay = 0.f, bx = 0.f, by = 0.f;
    float cx = 0.f, cy = 0.f, dx = 0.f, dy = 0.f;
    int e = beg;
    for (; e + 8 <= end; e += 8) {
        float2 p[8];
#pragma unroll
        for (int j = 0; j < 8; ++j) p[j] = ew[e + j];          // uniform -> s_load
        __half2 hv[8];
#pragma unroll
        for (int j = 0; j < 8; ++j) {
            const __half2* r = (const __half2*)(hin + (size_t)__float_as_int(p[j].y) * D_DATA);
            hv[j] = act ? r[lane] : __half2();
        }
        float2 v[8];
#pragma unroll
        for (int j = 0; j < 8; ++j) v[j] = __half22float2(hv[j]);
        ax += p[0].x * v[0].x; ay += p[0].x * v[0].y;
        bx += p[1].x * v[1].x; by += p[1].x * v[1].y;
        cx += p[2].x * v[2].x; cy += p[2].x * v[2].y;
        dx += p[3].x * v[3].x; dy += p[3].x * v[3].y;
        ax += p[4].x * v[4].x; ay += p[4].x * v[4].y;
        bx += p[5].x * v[5].x; by += p[5].x * v[5].y;
        cx += p[6].x * v[6].x; cy += p[6].x * v[6].y;
        dx += p[7].x * v[7].x; dy += p[7].x * v[7].y;
    }
    for (; e < end; ++e) {
        float2 p = ew[e];
        const __half2* r = (const __half2*)(hin + (size_t)__float_as_int(p.y) * D_DATA);
        __half2 h2 = act ? r[lane] : __half2();
        float2 v = __half22float2(h2);
        ax += p.x * v.x; ay += p.x * v.y;
    }
    if (act) {
        float sx = (ax + bx) + (cx + dx);
        float sy = (ay + by) + (cy + dy);
        const float2* x2 = (const float2*)(x + (size_t)node * D_DATA);
        float2 xv = x2[lane];
        float2 o = make_float2(sx + ALPHA * xv.x, sy + ALPHA * xv.y);
        ((__half2*)(hout + (size_t)node * D_DATA))[lane] = __float22half2_rn(o);
    }
}

// final step: same gather, fp32 output for the MLP
__global__ __launch_bounds__(256) void prop_final_kernel(
        const __half* __restrict__ hin, const float* __restrict__ x,
        const int* __restrict__ row_ptr, const float2* __restrict__ ew,
        float* __restrict__ hout, int n_nodes) {
    int lane = threadIdx.x & 63;
    int node = __builtin_amdgcn_readfirstlane(blockIdx.x * 4 + (threadIdx.x >> 6));
    if (node >= n_nodes) return;
    int beg = __builtin_amdgcn_readfirstlane(row_ptr[node]);
    int end = __builtin_amdgcn_readfirstlane(row_ptr[node + 1]);
    bool act = lane < (D_DATA / 2);
    float ax = 0.f, ay = 0.f, bx = 0.f, by = 0.f;
    float cx = 0.f, cy = 0.f, dx = 0.f, dy = 0.f;
    int e = beg;
    for (; e + 8 <= end; e += 8) {
        float2 p[8];
#pragma unroll
        for (int j = 0; j < 8; ++j) p[j] = ew[e + j];
        __half2 hv[8];
#pragma unroll
        for (int j = 0; j < 8; ++j) {
            const __half2* r = (const __half2*)(hin + (size_t)__float_as_int(p[j].y) * D_DATA);
            hv[j] = act ? r[lane] : __half2();
        }
        float2 v[8];
#pragma unroll
        for (int j = 0; j < 8; ++j) v[j] = __half22float2(hv[j]);
        ax += p[0].x * v[0].x; ay += p[0].x * v[0].y;
        bx += p[1].x * v[1].x; by += p[1].x * v[1].y;
        cx += p[2].x * v[2].x; cy += p[2].x * v[2].y;
        dx += p[3].x * v[3].x; dy += p[3].x * v[3].y;
        ax += p[4].x * v[4].x; ay += p[4].x * v[4].y;
        bx += p[5].x * v[5].x; by += p[5].x * v[5].y;
        cx += p[6].x * v[6].x; cy += p[6].x * v[6].y;
        dx += p[7].x * v[7].x; dy += p[7].x * v[7].y;
    }
    for (; e < end; ++e) {
        float2 p = ew[e];
        const __half2* r = (const __half2*)(hin + (size_t)__float_as_int(p.y) * D_DATA);
        __half2 h2 = act ? r[lane] : __half2();
        float2 v = __half22float2(h2);
        ax += p.x * v.x; ay += p.x * v.y;
    }
    if (act) {
        float sx = (ax + bx) + (cx + dx);
        float sy = (ay + by) + (cy + dy);
        const float2* x2 = (const float2*)(x + (size_t)node * D_DATA);
        float2 xv = x2[lane];
        float2 o = make_float2(sx + ALPHA * xv.x, sy + ALPHA * xv.y);
        ((float2*)(hout + (size_t)node * D_DATA))[lane] = o;
    }
}

// ---------------- fused MLP (unchanged from R5) ----------------

#define TN 32
#define HP 260

__global__ __launch_bounds__(256, 4) void mlp_kernel(
        const float* __restrict__ h,
        const float* __restrict__ W1, const float* __restrict__ b1,
        const float* __restrict__ W2t, const float* __restrict__ b2,
        float* __restrict__ out, int n_nodes) {
    __shared__ float zs[TN][HP];   // 32.5 KB -> 4 blocks/CU
    int tid = threadIdx.x;
    int node0 = blockIdx.x * TN;

    // ---- phase 1: z = relu(h @ W1 + b1) ----
    {
        int cg = tid & 63;
        int ng = tid >> 6;
        const float4* hrow[8];
#pragma unroll
        for (int i = 0; i < 8; ++i) {
            int r = __builtin_amdgcn_readfirstlane(node0 + ng * 8 + i);
            hrow[i] = (const float4*)(h + (size_t)r * D_DATA);
        }
        float acc[8][4];
        float4 bv = *(const float4*)(b1 + 4 * cg);
#pragma unroll
        for (int i = 0; i < 8; ++i) {
            acc[i][0] = bv.x; acc[i][1] = bv.y; acc[i][2] = bv.z; acc[i][3] = bv.w;
        }
        float4 wv[4], wn[4];
#pragma unroll
        for (int k = 0; k < 4; ++k)
            wv[k] = *(const float4*)&W1[(size_t)k * H_DIM + 4 * cg];
        for (int d4 = 0; d4 < D_DATA / 4; ++d4) {
            if (d4 + 1 < D_DATA / 4) {
#pragma unroll
                for (int k = 0; k < 4; ++k)
                    wn[k] = *(const float4*)&W1[(size_t)((d4 + 1) * 4 + k) * H_DIM + 4 * cg];
            }
            float4 hv[8];
#pragma unroll
            for (int i = 0; i < 8; ++i) hv[i] = hrow[i][d4];   // scalar pipe
#pragma unroll
            for (int i = 0; i < 8; ++i) {
                acc[i][0] += hv[i].x * wv[0].x + hv[i].y * wv[1].x + hv[i].z * wv[2].x + hv[i].w * wv[3].x;
                acc[i][1] += hv[i].x * wv[0].y + hv[i].y * wv[1].y + hv[i].z * wv[2].y + hv[i].w * wv[3].y;
                acc[i][2] += hv[i].x * wv[0].z + hv[i].y * wv[1].z + hv[i].z * wv[2].z + hv[i].w * wv[3].z;
                acc[i][3] += hv[i].x * wv[0].w + hv[i].y * wv[1].w + hv[i].z * wv[2].w + hv[i].w * wv[3].w;
            }
#pragma unroll
            for (int k = 0; k < 4; ++k) wv[k] = wn[k];
        }
#pragma unroll
        for (int i = 0; i < 8; ++i) {
            float4 t;
            t.x = fmaxf(acc[i][0], 0.f); t.y = fmaxf(acc[i][1], 0.f);
            t.z = fmaxf(acc[i][2], 0.f); t.w = fmaxf(acc[i][3], 0.f);
            *(float4*)&zs[ng * 8 + i][4 * cg] = t;
        }
    }
    __syncthreads();

    // ---- phase 2: out = z @ W2 + b2 ----
    {
        int cg2 = tid >> 4;
        int ng2 = tid & 15;
        int col0 = cg2 * 3;
        int nA = ng2, nB = ng2 + 16;   // lane stride 260 dwords: 2-way (free)
        float acc2[2][3];
#pragma unroll
        for (int cc = 0; cc < 3; ++cc) {
            int c = col0 + cc;
            float bb = (c < N_CLS) ? b2[c] : 0.f;
            acc2[0][cc] = bb; acc2[1][cc] = bb;
        }
        for (int j4 = 0; j4 < H_DIM / 4; ++j4) {
            float4 z0 = *(const float4*)&zs[nA][j4 * 4];
            float4 z1 = *(const float4*)&zs[nB][j4 * 4];
#pragma unroll
            for (int cc = 0; cc < 3; ++cc) {
                float4 w = *(const float4*)&W2t[(size_t)(col0 + cc) * H_DIM + j4 * 4];
                acc2[0][cc] += z0.x * w.x + z0.y * w.y + z0.z * w.z + z0.w * w.w;
                acc2[1][cc] += z1.x * w.x + z1.y * w.y + z1.z * w.z + z1.w * w.w;
            }
        }
#pragma unroll
        for (int n = 0; n < 2; ++n)
#pragma unroll
            for (int cc = 0; cc < 3; ++cc) {
                int c = col0 + cc;
                int gn = node0 + (n == 0 ? nA : nB);
                if (c < N_CLS && gn < n_nodes)
                    out[(size_t)gn * N_CLS + c] = acc2[n][cc];
            }
    }
}

// ---------------- launch ----------------

static inline size_t align_up(size_t v, size_t a) { return (v + a - 1) & ~(a - 1); }

extern "C" void kernel_launch(void* const* d_in, const int* in_sizes, int n_in,
                              void* d_out, int out_size, void* d_ws, size_t ws_size,
                              hipStream_t stream) {
    const float* x   = (const float*)d_in[0];
    const int*   src = (const int*)d_in[1];
    const int*   dst = (const int*)d_in[2];
    const float* W1  = (const float*)d_in[3];
    const float* b1  = (const float*)d_in[4];
    const float* W2  = (const float*)d_in[5];
    const float* b2  = (const float*)d_in[6];
    float* out = (float*)d_out;

    char* p = (char*)d_ws;
    size_t off = 0;
    int* deg = (int*)(p + off);           off = align_up(off + N_NODES * 4, 256);
    int* row_ptr = (int*)(p + off);       off = align_up(off + (N_NODES + 1) * 4, 256);
    int* fill = (int*)(p + off);          off = align_up(off + N_NODES * 4, 256);
    float* norm = (float*)(p + off);      off = align_up(off + N_NODES * 4, 256);
    int* partials = (int*)(p + off);      off = align_up(off + SCAN_NB * 4, 256);
    int* pofs = (int*)(p + off);          off = align_up(off + SCAN_NB * 4, 256);
    float2* ew = (float2*)(p + off);      off = align_up(off + N_EDGES * 8, 256);
    // fp16 buffers: x16 and h16B adjacent so hF (fp32, 40MB) can overlay both
    // after they are dead (x16 dead after step 0, h16B dead after step 8).
    __half* x16 = (__half*)(p + off);     size_t x16_off = off;
                                          off = align_up(off + (size_t)N_NODES * D_DATA * 2, 256);
    __half* h16B = (__half*)(p + off);    off = align_up(off + (size_t)N_NODES * D_DATA * 2, 256);
    __half* h16A = (__half*)(p + off);    off = align_up(off + (size_t)N_NODES * D_DATA * 2, 256);
    float* hF = (float*)(p + x16_off);    // 40MB over [x16, h16B]
    (void)ws_size;
    float* W2t = (float*)fill;   // fill is dead after scatter_kernel

    hipMemsetAsync(deg, 0, N_NODES * 4, stream);
    hipMemsetAsync(fill, 0, N_NODES * 4, stream);

    int eb = (N_EDGES + 255) / 256;
    deg_kernel<<<eb, 256, 0, stream>>>(dst, deg, N_EDGES);
    scan_partial_kernel<<<SCAN_NB, 256, 0, stream>>>(deg, partials);
    scan_top_kernel<<<1, 256, 0, stream>>>(partials, pofs, row_ptr);
    scan_emit_kernel<<<SCAN_NB, 256, 0, stream>>>(deg, pofs, row_ptr, norm);
    scatter_kernel<<<eb, 256, 0, stream>>>(src, dst, norm, row_ptr, fill, ew, N_EDGES);
    transpose_w2_kernel<<<(48 * H_DIM + 255) / 256, 256, 0, stream>>>(W2, W2t);

    int nh2 = N_NODES * D_DATA / 2;   // 5,000,000 half2
    convert_x16_kernel<<<(nh2 + 255) / 256, 256, 0, stream>>>((const float2*)x, (__half2*)x16, nh2);

    int pb = N_NODES / 4;   // 4 waves (nodes) per block
    // k=0: x16->A; odd k: A->B; even k: B->A; k=9 reads A, writes hF (fp32)
    prop16_kernel<<<pb, 256, 0, stream>>>(x16, x, row_ptr, ew, h16A, N_NODES);
    const __half* hin = h16A;
    for (int k = 1; k < K_STEPS - 1; ++k) {
        __half* ho = (k & 1) ? h16B : h16A;
        prop16_kernel<<<pb, 256, 0, stream>>>(hin, x, row_ptr, ew, ho, N_NODES);
        hin = ho;
    }
    // after k=8 (even), hin == h16A
    prop_final_kernel<<<pb, 256, 0, stream>>>(hin, x, row_ptr, ew, hF, N_NODES);

    int mb = N_NODES / TN;
    mlp_kernel<<<mb, 256, 0, stream>>>(hF, W1, b1, W2t, b2, out, N_NODES);
}

// Round 7
// 731.199 us; speedup vs baseline: 1.3192x; 1.1031x over previous
//
#include <hip/hip_runtime.h>
#include <hip/hip_fp16.h>

// APPNP: K steps of D^{-1/2} A D^{-1/2} propagation + teleport, then MLP.
// R7: (a) fp16 h rows stored at stride 128 halfs (256B, 256B-aligned -> every
// gather is exactly 2 cache lines; all 64 lanes active, pad cols are zeros);
// (b) CSR padded to a multiple of 4 with weight-0 edges -> edge loop is exact
// 8/4-wide batches, no serial scalar tail (mean deg 8 made ~45% of nodes hit
// a ~3.5-deep dependent-load tail before).

#define N_NODES 100000
#define N_EDGES 800000
#define D_DATA  100
#define H_DIM   256
#define N_CLS   47
#define K_STEPS 10
#define ALPHA   0.1f
#define HS      128      // fp16 h row stride (halfs); cols 100..127 are zero

#define SCAN_NB    200
#define SCAN_CHUNK 500   // 200*500 == N_NODES
#define EW_CAP (N_EDGES + 3 * N_NODES)   // padded-CSR worst case

// ---------------- CSR build ----------------

__global__ void deg_kernel(const int* __restrict__ dst, int* __restrict__ deg, int e) {
    int i = blockIdx.x * blockDim.x + threadIdx.x;
    if (i < e) atomicAdd(&deg[dst[i]], 1);
}

// pass 1: per-block sums of padded deg (round up to multiple of 4)
__global__ __launch_bounds__(256) void scan_partial_kernel(
        const int* __restrict__ deg, int* __restrict__ partials) {
    __shared__ int red[256];
    int t = threadIdx.x;
    int base = blockIdx.x * SCAN_CHUNK;
    int s = 0;
    int i0 = 2 * t, i1 = 2 * t + 1;
    if (i0 < SCAN_CHUNK) s += (deg[base + i0] + 3) & ~3;
    if (i1 < SCAN_CHUNK) s += (deg[base + i1] + 3) & ~3;
    red[t] = s;
    __syncthreads();
    for (int off = 128; off > 0; off >>= 1) {
        if (t < off) red[t] += red[t + off];
        __syncthreads();
    }
    if (t == 0) partials[blockIdx.x] = red[0];
}

// pass 2: single block scans the 200 partials (exclusive); total -> row_ptr[N]
__global__ __launch_bounds__(256) void scan_top_kernel(
        const int* __restrict__ partials, int* __restrict__ pofs,
        int* __restrict__ row_ptr) {
    __shared__ int s[256];
    int t = threadIdx.x;
    s[t] = (t < SCAN_NB) ? partials[t] : 0;
    __syncthreads();
    for (int off = 1; off < 256; off <<= 1) {
        int v = (t >= off) ? s[t - off] : 0;
        __syncthreads();
        s[t] += v;
        __syncthreads();
    }
    if (t < SCAN_NB) pofs[t] = s[t] - partials[t];
    if (t == SCAN_NB - 1) row_ptr[N_NODES] = s[t];   // padded total
}

// pass 3: block-local exclusive scan of padded deg + emit row_ptr and norm
__global__ __launch_bounds__(256) void scan_emit_kernel(
        const int* __restrict__ deg, const int* __restrict__ pofs,
        int* __restrict__ row_ptr, float* __restrict__ norm) {
    __shared__ int s[256];
    int t = threadIdx.x;
    int base = blockIdx.x * SCAN_CHUNK;
    int i0 = 2 * t, i1 = 2 * t + 1;
    int d0 = (i0 < SCAN_CHUNK) ? deg[base + i0] : 0;
    int d1 = (i1 < SCAN_CHUNK) ? deg[base + i1] : 0;
    int p0 = (d0 + 3) & ~3, p1 = (d1 + 3) & ~3;
    s[t] = p0 + p1;
    __syncthreads();
    for (int off = 1; off < 256; off <<= 1) {
        int v = (t >= off) ? s[t - off] : 0;
        __syncthreads();
        s[t] += v;
        __syncthreads();
    }
    int p = s[t] - (p0 + p1) + pofs[blockIdx.x];
    if (i0 < SCAN_CHUNK) {
        row_ptr[base + i0] = p;
        norm[base + i0] = rsqrtf((float)max(d0, 1));
    }
    if (i1 < SCAN_CHUNK) {
        row_ptr[base + i1] = p + p0;
        norm[base + i1] = rsqrtf((float)max(d1, 1));
    }
}

__global__ void scatter_kernel(const int* __restrict__ src, const int* __restrict__ dst,
                               const float* __restrict__ norm,
                               const int* __restrict__ row_ptr, int* __restrict__ fill,
                               float2* __restrict__ ew, int e) {
    int i = blockIdx.x * blockDim.x + threadIdx.x;
    if (i < e) {
        int d = dst[i], s = src[i];
        int pos = row_ptr[d] + atomicAdd(&fill[d], 1);
        float w = (1.0f - ALPHA) * norm[s] * norm[d];
        ew[pos] = make_float2(w, __int_as_float(s));
    }
}

// fill pad slots [row_ptr[i]+deg[i], row_ptr[i+1]) with weight-0 edges to node 0
__global__ void pad_kernel(const int* __restrict__ deg, const int* __restrict__ row_ptr,
                           float2* __restrict__ ew, int n) {
    int i = blockIdx.x * blockDim.x + threadIdx.x;
    if (i < n) {
        int b = row_ptr[i] + deg[i];
        int e = row_ptr[i + 1];
        for (int s = b; s < e; ++s) ew[s] = make_float2(0.f, __int_as_float(0));
    }
}

__global__ void transpose_w2_kernel(const float* __restrict__ W2, float* __restrict__ W2t) {
    int idx = blockIdx.x * blockDim.x + threadIdx.x;
    if (idx < 48 * H_DIM) {
        int c = idx >> 8;
        int j = idx & (H_DIM - 1);
        W2t[c * H_DIM + j] = (c < N_CLS) ? W2[j * N_CLS + c] : 0.f;
    }
}

// x (fp32, dense stride 100) -> x16 (fp16, stride 128, zero pad cols)
__global__ void convert_x16_kernel(const float* __restrict__ x,
                                   __half2* __restrict__ x16, int n_half2) {
    int i = blockIdx.x * blockDim.x + threadIdx.x;
    if (i < n_half2) {
        int node = i >> 6;          // 64 half2 per row
        int c2 = i & 63;            // half2 index in row
        float2 v = make_float2(0.f, 0.f);
        if (c2 < D_DATA / 2) {
            const float2* r = (const float2*)(x + (size_t)node * D_DATA);
            v = r[c2];
        }
        x16[i] = __float22half2_rn(v);
    }
}

// ---------------- propagation ----------------
// One wave per node; all 64 lanes: lane l holds half2 l of the 256B row.
// Padded CSR -> exact 8-wide then 4-wide batches, no scalar tail.

__global__ __launch_bounds__(256) void prop16_kernel(
        const __half* __restrict__ hin, const float* __restrict__ x,
        const int* __restrict__ row_ptr, const float2* __restrict__ ew,
        __half* __restrict__ hout, int n_nodes) {
    int lane = threadIdx.x & 63;
    int node = __builtin_amdgcn_readfirstlane(blockIdx.x * 4 + (threadIdx.x >> 6));
    if (node >= n_nodes) return;
    int beg = __builtin_amdgcn_readfirstlane(row_ptr[node]);
    int end = __builtin_amdgcn_readfirstlane(row_ptr[node + 1]);
    float ax = 0.f, ay = 0.f, bx = 0.f, by = 0.f;
    float cx = 0.f, cy = 0.f, dx = 0.f, dy = 0.f;
    int e = beg;
    for (; e + 8 <= end; e += 8) {
        float2 p[8];
#pragma unroll
        for (int j = 0; j < 8; ++j) p[j] = ew[e + j];          // uniform -> s_load
        __half2 hv[8];
#pragma unroll
        for (int j = 0; j < 8; ++j) {
            const __half2* r = (const __half2*)(hin + (size_t)__float_as_int(p[j].y) * HS);
            hv[j] = r[lane];
        }
        float2 v[8];
#pragma unroll
        for (int j = 0; j < 8; ++j) v[j] = __half22float2(hv[j]);
        ax += p[0].x * v[0].x; ay += p[0].x * v[0].y;
        bx += p[1].x * v[1].x; by += p[1].x * v[1].y;
        cx += p[2].x * v[2].x; cy += p[2].x * v[2].y;
        dx += p[3].x * v[3].x; dy += p[3].x * v[3].y;
        ax += p[4].x * v[4].x; ay += p[4].x * v[4].y;
        bx += p[5].x * v[5].x; by += p[5].x * v[5].y;
        cx += p[6].x * v[6].x; cy += p[6].x * v[6].y;
        dx += p[7].x * v[7].x; dy += p[7].x * v[7].y;
    }
    if (e < end) {   // exactly one 4-batch (padded deg % 4 == 0)
        float2 p[4];
#pragma unroll
        for (int j = 0; j < 4; ++j) p[j] = ew[e + j];
        __half2 hv[4];
#pragma unroll
        for (int j = 0; j < 4; ++j) {
            const __half2* r = (const __half2*)(hin + (size_t)__float_as_int(p[j].y) * HS);
            hv[j] = r[lane];
        }
#pragma unroll
        for (int j = 0; j < 4; ++j) {
            float2 v = __half22float2(hv[j]);
            ax += p[j].x * v.x; ay += p[j].x * v.y;
        }
    }
    float sx = (ax + bx) + (cx + dx);
    float sy = (ay + by) + (cy + dy);
    // teleport only on real cols; pad cols stay exactly zero
    float2 xv = make_float2(0.f, 0.f);
    if (lane < D_DATA / 2)
        xv = ((const float2*)(x + (size_t)node * D_DATA))[lane];
    float2 o = make_float2(sx + ALPHA * xv.x, sy + ALPHA * xv.y);
    ((__half2*)(hout + (size_t)node * HS))[lane] = __float22half2_rn(o);
}

// final step: same gather, fp32 dense output for the MLP
__global__ __launch_bounds__(256) void prop_final_kernel(
        const __half* __restrict__ hin, const float* __restrict__ x,
        const int* __restrict__ row_ptr, const float2* __restrict__ ew,
        float* __restrict__ hout, int n_nodes) {
    int lane = threadIdx.x & 63;
    int node = __builtin_amdgcn_readfirstlane(blockIdx.x * 4 + (threadIdx.x >> 6));
    if (node >= n_nodes) return;
    int beg = __builtin_amdgcn_readfirstlane(row_ptr[node]);
    int end = __builtin_amdgcn_readfirstlane(row_ptr[node + 1]);
    float ax = 0.f, ay = 0.f, bx = 0.f, by = 0.f;
    float cx = 0.f, cy = 0.f, dx = 0.f, dy = 0.f;
    int e = beg;
    for (; e + 8 <= end; e += 8) {
        float2 p[8];
#pragma unroll
        for (int j = 0; j < 8; ++j) p[j] = ew[e + j];
        __half2 hv[8];
#pragma unroll
        for (int j = 0; j < 8; ++j) {
            const __half2* r = (const __half2*)(hin + (size_t)__float_as_int(p[j].y) * HS);
            hv[j] = r[lane];
        }
        float2 v[8];
#pragma unroll
        for (int j = 0; j < 8; ++j) v[j] = __half22float2(hv[j]);
        ax += p[0].x * v[0].x; ay += p[0].x * v[0].y;
        bx += p[1].x * v[1].x; by += p[1].x * v[1].y;
        cx += p[2].x * v[2].x; cy += p[2].x * v[2].y;
        dx += p[3].x * v[3].x; dy += p[3].x * v[3].y;
        ax += p[4].x * v[4].x; ay += p[4].x * v[4].y;
        bx += p[5].x * v[5].x; by += p[5].x * v[5].y;
        cx += p[6].x * v[6].x; cy += p[6].x * v[6].y;
        dx += p[7].x * v[7].x; dy += p[7].x * v[7].y;
    }
    if (e < end) {
        float2 p[4];
#pragma unroll
        for (int j = 0; j < 4; ++j) p[j] = ew[e + j];
        __half2 hv[4];
#pragma unroll
        for (int j = 0; j < 4; ++j) {
            const __half2* r = (const __half2*)(hin + (size_t)__float_as_int(p[j].y) * HS);
            hv[j] = r[lane];
        }
#pragma unroll
        for (int j = 0; j < 4; ++j) {
            float2 v = __half22float2(hv[j]);
            ax += p[j].x * v.x; ay += p[j].x * v.y;
        }
    }
    if (lane < D_DATA / 2) {
        float sx = (ax + bx) + (cx + dx);
        float sy = (ay + by) + (cy + dy);
        float2 xv = ((const float2*)(x + (size_t)node * D_DATA))[lane];
        float2 o = make_float2(sx + ALPHA * xv.x, sy + ALPHA * xv.y);
        ((float2*)(hout + (size_t)node * D_DATA))[lane] = o;
    }
}

// ---------------- fused MLP (unchanged from R5/R6) ----------------

#define TN 32
#define HP 260

__global__ __launch_bounds__(256, 4) void mlp_kernel(
        const float* __restrict__ h,
        const float* __restrict__ W1, const float* __restrict__ b1,
        const float* __restrict__ W2t, const float* __restrict__ b2,
        float* __restrict__ out, int n_nodes) {
    __shared__ float zs[TN][HP];   // 32.5 KB -> 4 blocks/CU
    int tid = threadIdx.x;
    int node0 = blockIdx.x * TN;

    // ---- phase 1: z = relu(h @ W1 + b1) ----
    {
        int cg = tid & 63;
        int ng = tid >> 6;
        const float4* hrow[8];
#pragma unroll
        for (int i = 0; i < 8; ++i) {
            int r = __builtin_amdgcn_readfirstlane(node0 + ng * 8 + i);
            hrow[i] = (const float4*)(h + (size_t)r * D_DATA);
        }
        float acc[8][4];
        float4 bv = *(const float4*)(b1 + 4 * cg);
#pragma unroll
        for (int i = 0; i < 8; ++i) {
            acc[i][0] = bv.x; acc[i][1] = bv.y; acc[i][2] = bv.z; acc[i][3] = bv.w;
        }
        float4 wv[4], wn[4];
#pragma unroll
        for (int k = 0; k < 4; ++k)
            wv[k] = *(const float4*)&W1[(size_t)k * H_DIM + 4 * cg];
        for (int d4 = 0; d4 < D_DATA / 4; ++d4) {
            if (d4 + 1 < D_DATA / 4) {
#pragma unroll
                for (int k = 0; k < 4; ++k)
                    wn[k] = *(const float4*)&W1[(size_t)((d4 + 1) * 4 + k) * H_DIM + 4 * cg];
            }
            float4 hv[8];
#pragma unroll
            for (int i = 0; i < 8; ++i) hv[i] = hrow[i][d4];   // scalar pipe
#pragma unroll
            for (int i = 0; i < 8; ++i) {
                acc[i][0] += hv[i].x * wv[0].x + hv[i].y * wv[1].x + hv[i].z * wv[2].x + hv[i].w * wv[3].x;
                acc[i][1] += hv[i].x * wv[0].y + hv[i].y * wv[1].y + hv[i].z * wv[2].y + hv[i].w * wv[3].y;
                acc[i][2] += hv[i].x * wv[0].z + hv[i].y * wv[1].z + hv[i].z * wv[2].z + hv[i].w * wv[3].z;
                acc[i][3] += hv[i].x * wv[0].w + hv[i].y * wv[1].w + hv[i].z * wv[2].w + hv[i].w * wv[3].w;
            }
#pragma unroll
            for (int k = 0; k < 4; ++k) wv[k] = wn[k];
        }
#pragma unroll
        for (int i = 0; i < 8; ++i) {
            float4 t;
            t.x = fmaxf(acc[i][0], 0.f); t.y = fmaxf(acc[i][1], 0.f);
            t.z = fmaxf(acc[i][2], 0.f); t.w = fmaxf(acc[i][3], 0.f);
            *(float4*)&zs[ng * 8 + i][4 * cg] = t;
        }
    }
    __syncthreads();

    // ---- phase 2: out = z @ W2 + b2 ----
    {
        int cg2 = tid >> 4;
        int ng2 = tid & 15;
        int col0 = cg2 * 3;
        int nA = ng2, nB = ng2 + 16;   // lane stride 260 dwords: 2-way (free)
        float acc2[2][3];
#pragma unroll
        for (int cc = 0; cc < 3; ++cc) {
            int c = col0 + cc;
            float bb = (c < N_CLS) ? b2[c] : 0.f;
            acc2[0][cc] = bb; acc2[1][cc] = bb;
        }
        for (int j4 = 0; j4 < H_DIM / 4; ++j4) {
            float4 z0 = *(const float4*)&zs[nA][j4 * 4];
            float4 z1 = *(const float4*)&zs[nB][j4 * 4];
#pragma unroll
            for (int cc = 0; cc < 3; ++cc) {
                float4 w = *(const float4*)&W2t[(size_t)(col0 + cc) * H_DIM + j4 * 4];
                acc2[0][cc] += z0.x * w.x + z0.y * w.y + z0.z * w.z + z0.w * w.w;
                acc2[1][cc] += z1.x * w.x + z1.y * w.y + z1.z * w.z + z1.w * w.w;
            }
        }
#pragma unroll
        for (int n = 0; n < 2; ++n)
#pragma unroll
            for (int cc = 0; cc < 3; ++cc) {
                int c = col0 + cc;
                int gn = node0 + (n == 0 ? nA : nB);
                if (c < N_CLS && gn < n_nodes)
                    out[(size_t)gn * N_CLS + c] = acc2[n][cc];
            }
    }
}

// ---------------- launch ----------------

static inline size_t align_up(size_t v, size_t a) { return (v + a - 1) & ~(a - 1); }

extern "C" void kernel_launch(void* const* d_in, const int* in_sizes, int n_in,
                              void* d_out, int out_size, void* d_ws, size_t ws_size,
                              hipStream_t stream) {
    const float* x   = (const float*)d_in[0];
    const int*   src = (const int*)d_in[1];
    const int*   dst = (const int*)d_in[2];
    const float* W1  = (const float*)d_in[3];
    const float* b1  = (const float*)d_in[4];
    const float* W2  = (const float*)d_in[5];
    const float* b2  = (const float*)d_in[6];
    float* out = (float*)d_out;

    char* p = (char*)d_ws;
    size_t off = 0;
    int* deg = (int*)(p + off);           off = align_up(off + N_NODES * 4, 256);
    int* row_ptr = (int*)(p + off);       off = align_up(off + (N_NODES + 1) * 4, 256);
    int* fill = (int*)(p + off);          off = align_up(off + N_NODES * 4, 256);
    float* norm = (float*)(p + off);      off = align_up(off + N_NODES * 4, 256);
    int* partials = (int*)(p + off);      off = align_up(off + SCAN_NB * 4, 256);
    int* pofs = (int*)(p + off);          off = align_up(off + SCAN_NB * 4, 256);
    float2* ew = (float2*)(p + off);      off = align_up(off + (size_t)EW_CAP * 8, 256);
    // fp16 buffers (stride-128 rows, 25.6MB each); x16 and h16B adjacent so
    // hF (fp32 dense, 40MB) overlays them once both are dead (x16 after k=0,
    // h16B after k=8).
    __half* x16 = (__half*)(p + off);     size_t x16_off = off;
                                          off = align_up(off + (size_t)N_NODES * HS * 2, 256);
    __half* h16B = (__half*)(p + off);    off = align_up(off + (size_t)N_NODES * HS * 2, 256);
    __half* h16A = (__half*)(p + off);    off = align_up(off + (size_t)N_NODES * HS * 2, 256);
    float* hF = (float*)(p + x16_off);
    (void)ws_size;
    float* W2t = (float*)fill;   // fill is dead after scatter_kernel

    hipMemsetAsync(deg, 0, N_NODES * 4, stream);
    hipMemsetAsync(fill, 0, N_NODES * 4, stream);

    int eb = (N_EDGES + 255) / 256;
    deg_kernel<<<eb, 256, 0, stream>>>(dst, deg, N_EDGES);
    scan_partial_kernel<<<SCAN_NB, 256, 0, stream>>>(deg, partials);
    scan_top_kernel<<<1, 256, 0, stream>>>(partials, pofs, row_ptr);
    scan_emit_kernel<<<SCAN_NB, 256, 0, stream>>>(deg, pofs, row_ptr, norm);
    scatter_kernel<<<eb, 256, 0, stream>>>(src, dst, norm, row_ptr, fill, ew, N_EDGES);
    pad_kernel<<<(N_NODES + 255) / 256, 256, 0, stream>>>(deg, row_ptr, ew, N_NODES);
    transpose_w2_kernel<<<(48 * H_DIM + 255) / 256, 256, 0, stream>>>(W2, W2t);

    int nh2 = N_NODES * HS / 2;
    convert_x16_kernel<<<(nh2 + 255) / 256, 256, 0, stream>>>(x, (__half2*)x16, nh2);

    int pb = N_NODES / 4;   // 4 waves (nodes) per block
    prop16_kernel<<<pb, 256, 0, stream>>>(x16, x, row_ptr, ew, h16A, N_NODES);
    const __half* hin = h16A;
    for (int k = 1; k < K_STEPS - 1; ++k) {
        __half* ho = (k & 1) ? h16B : h16A;
        prop16_kernel<<<pb, 256, 0, stream>>>(hin, x, row_ptr, ew, ho, N_NODES);
        hin = ho;
    }
    // after k=8 (even), hin == h16A; k=9 writes fp32 dense hF
    prop_final_kernel<<<pb, 256, 0, stream>>>(hin, x, row_ptr, ew, hF, N_NODES);

    int mb = N_NODES / TN;
    mlp_kernel<<<mb, 256, 0, stream>>>(hF, W1, b1, W2t, b2, out, N_NODES);
}